// Round 1
// baseline (857.264 us; speedup 1.0000x reference)
//
#include <hip/hip_runtime.h>
#include <math.h>

#define V_N 100000
#define D_N 300
#define K_N 200
#define B_N 256

// ---------------- workspace layout (floats) ----------------
// P   : K_N * V_N            (logp, row-major K x V)
// coef: 3 * D_N * K_N        ([mat][d][k]; mat0=Dinv, mat1=mu*Dinv, mat2=u)
// alpha, s, hic, m, z : K_N each
// yT  : K_N * B_N            (x[b][k]/Z[k], transposed K x B)
static constexpr size_t P_OFF     = 0;
static constexpr size_t COEF_OFF  = (size_t)K_N * V_N;
static constexpr size_t ALPHA_OFF = COEF_OFF + (size_t)3 * D_N * K_N;
static constexpr size_t S_OFF     = ALPHA_OFF + K_N;
static constexpr size_t HIC_OFF   = S_OFF + K_N;
static constexpr size_t M_OFF     = HIC_OFF + K_N;
static constexpr size_t Z_OFF     = M_OFF + K_N;
static constexpr size_t YT_OFF    = Z_OFF + K_N;

// ---------------- kernel A: per-topic prep ----------------
__global__ __launch_bounds__(256) void topic_prep(
    const float* __restrict__ mu, const float* __restrict__ w,
    const float* __restrict__ diag, float* __restrict__ coef,
    float* __restrict__ alpha, float* __restrict__ sArr,
    float* __restrict__ hic)
{
    int k = blockIdx.x;
    int tid = threadIdx.x;
    float capp = 0.f, logd = 0.f, cpart = 0.f, spart = 0.f;
    for (int d = tid; d < D_N; d += 256) {
        float Dg = diag[k * D_N + d];
        float Di = 1.0f / Dg;
        float wv = w[k * D_N + d];
        float m  = mu[k * D_N + d];
        float u  = wv * Di;
        capp  += wv * u;          // w^2 * Dinv
        logd  += logf(Dg);
        cpart += m * m * Di;
        spart += m * u;
        coef[0 * D_N * K_N + (size_t)d * K_N + k] = Di;
        coef[1 * D_N * K_N + (size_t)d * K_N + k] = m * Di;
        coef[2 * D_N * K_N + (size_t)d * K_N + k] = u;
    }
    __shared__ float4 red[256];
    red[tid] = make_float4(capp, logd, cpart, spart);
    __syncthreads();
    for (int s = 128; s > 0; s >>= 1) {
        if (tid < s) {
            float4 a = red[tid], b = red[tid + s];
            red[tid] = make_float4(a.x + b.x, a.y + b.y, a.z + b.z, a.w + b.w);
        }
        __syncthreads();
    }
    if (tid == 0) {
        float4 r = red[0];
        float cap = 1.0f + r.x;
        float logdet = r.y + logf(cap);
        const float LOG2PI = 1.8378770664093453f;
        alpha[k] = -0.5f * ((float)D_N * LOG2PI + logdet + r.z);
        sArr[k]  = r.w;
        hic[k]   = 0.5f / cap;
    }
}

// ---------------- kernel B: logp (the flop hog) ----------------
#define TB_V 128
#define TB_K 32
#define DC   32

__global__ __launch_bounds__(256) void logp_kernel(
    const float* __restrict__ wv, const float* __restrict__ coef,
    const float* __restrict__ alpha, const float* __restrict__ sArr,
    const float* __restrict__ hic, float* __restrict__ P)
{
    __shared__ float As[DC][TB_V + 4];        // 32 x 132, transposed A chunk
    __shared__ float Bs[3][DC][TB_K + 4];     // 3 x 32 x 36

    int tid = threadIdx.x;
    int k0 = blockIdx.x * TB_K;   // fast dim = k-tiles (share A tile in L2)
    int v0 = blockIdx.y * TB_V;
    int vg = tid & 31;            // 32 v-groups of 4
    int kg = tid >> 5;            // 8 k-groups of 4

    float acc1[4][4] = {{0.f}};   // sum a^2 * Dinv
    float acc2[4][4] = {{0.f}};   // sum a * (mu*Dinv)
    float acc3[4][4] = {{0.f}};   // sum a * u

    for (int d0 = 0; d0 < D_N; d0 += DC) {
        // stage A: 128 v x 32 d, transposed into LDS
        {
            int idx = tid;
            #pragma unroll
            for (int it = 0; it < 4; ++it) {
                int v  = idx >> 3;       // 0..127
                int dq = idx & 7;        // float4 index in d
                int gv = v0 + v;
                int gd = d0 + dq * 4;
                float4 a = make_float4(0.f, 0.f, 0.f, 0.f);
                if (gv < V_N && gd + 3 < D_N) {
                    a = *(const float4*)(wv + (size_t)gv * D_N + gd);
                }
                As[dq * 4 + 0][v] = a.x;
                As[dq * 4 + 1][v] = a.y;
                As[dq * 4 + 2][v] = a.z;
                As[dq * 4 + 3][v] = a.w;
                idx += 256;
            }
        }
        // stage coef: 3 x 32 d x 32 k
        {
            int dr = tid >> 3;   // 0..31
            int kq = tid & 7;    // float4 in k
            int gd = d0 + dr;
            int gk = k0 + kq * 4;
            #pragma unroll
            for (int m = 0; m < 3; ++m) {
                float4 c = make_float4(0.f, 0.f, 0.f, 0.f);
                if (gd < D_N && gk + 3 < K_N) {
                    c = *(const float4*)(coef + (size_t)m * D_N * K_N
                                              + (size_t)gd * K_N + gk);
                }
                Bs[m][dr][kq * 4 + 0] = c.x;
                Bs[m][dr][kq * 4 + 1] = c.y;
                Bs[m][dr][kq * 4 + 2] = c.z;
                Bs[m][dr][kq * 4 + 3] = c.w;
            }
        }
        __syncthreads();

        #pragma unroll 8
        for (int d = 0; d < DC; ++d) {
            float4 a4 = *(const float4*)&As[d][vg * 4];
            float av[4] = {a4.x, a4.y, a4.z, a4.w};
            float4 c1 = *(const float4*)&Bs[0][d][kg * 4];
            float4 c2 = *(const float4*)&Bs[1][d][kg * 4];
            float4 c3 = *(const float4*)&Bs[2][d][kg * 4];
            float c1v[4] = {c1.x, c1.y, c1.z, c1.w};
            float c2v[4] = {c2.x, c2.y, c2.z, c2.w};
            float c3v[4] = {c3.x, c3.y, c3.z, c3.w};
            float asq[4];
            #pragma unroll
            for (int i = 0; i < 4; ++i) asq[i] = av[i] * av[i];
            #pragma unroll
            for (int i = 0; i < 4; ++i) {
                #pragma unroll
                for (int j = 0; j < 4; ++j) {
                    acc1[i][j] = fmaf(asq[i], c1v[j], acc1[i][j]);
                    acc2[i][j] = fmaf(av[i],  c2v[j], acc2[i][j]);
                    acc3[i][j] = fmaf(av[i],  c3v[j], acc3[i][j]);
                }
            }
        }
        __syncthreads();
    }

    // epilogue: logp = alpha - 0.5*acc1 + acc2 + hic * (acc3 - s)^2
    #pragma unroll
    for (int j = 0; j < 4; ++j) {
        int k = k0 + kg * 4 + j;
        if (k >= K_N) continue;
        float al = alpha[k], sk = sArr[k], hk = hic[k];
        int vb = v0 + vg * 4;
        float res[4];
        #pragma unroll
        for (int i = 0; i < 4; ++i) {
            float t = acc3[i][j] - sk;
            res[i] = al - 0.5f * acc1[i][j] + acc2[i][j] + hk * t * t;
        }
        if (vb + 3 < V_N) {
            *(float4*)(P + (size_t)k * V_N + vb)
                = make_float4(res[0], res[1], res[2], res[3]);
        } else {
            for (int i = 0; i < 4; ++i)
                if (vb + i < V_N) P[(size_t)k * V_N + vb + i] = res[i];
        }
    }
}

// ---------------- kernel C: per-topic online softmax stats ----------------
__global__ __launch_bounds__(1024) void softmax_stats(
    const float* __restrict__ P, float* __restrict__ mArr,
    float* __restrict__ zArr)
{
    int k = blockIdx.x;
    int tid = threadIdx.x;
    const float4* row = (const float4*)(P + (size_t)k * V_N);
    const int n4 = V_N / 4;  // 25000 exactly
    float m = -INFINITY, s = 0.f;
    for (int i = tid; i < n4; i += 1024) {
        float4 x = row[i];
        float mx = fmaxf(fmaxf(x.x, x.y), fmaxf(x.z, x.w));
        if (mx > m) { s *= __expf(m - mx); m = mx; }
        s += __expf(x.x - m) + __expf(x.y - m)
           + __expf(x.z - m) + __expf(x.w - m);
    }
    __shared__ float ms[1024], ss[1024];
    ms[tid] = m; ss[tid] = s;
    __syncthreads();
    for (int off = 512; off > 0; off >>= 1) {
        if (tid < off) {
            float mo = ms[tid], so = ss[tid];
            float m2 = ms[tid + off], s2 = ss[tid + off];
            float mn = fmaxf(mo, m2);
            ms[tid] = mn;
            ss[tid] = so * __expf(mo - mn) + s2 * __expf(m2 - mn);
        }
        __syncthreads();
    }
    if (tid == 0) { mArr[k] = ms[0]; zArr[k] = ss[0]; }
}

// ---------------- kernel C2: yT = x/Z, copy x into out ----------------
__global__ __launch_bounds__(256) void prep_y(
    const float* __restrict__ x, const float* __restrict__ zArr,
    float* __restrict__ yT, float* __restrict__ out)
{
    int idx = blockIdx.x * 256 + threadIdx.x;
    if (idx < B_N * K_N) {
        int b = idx / K_N, k = idx % K_N;
        float xv = x[idx];
        out[(size_t)b * (K_N + V_N) + k] = xv;
        yT[(size_t)k * B_N + b] = xv / zArr[k];
    }
}

// ---------------- kernel D: out[b, K+v] = sum_k y[b,k]*exp(P[k,v]-m[k]) ----
#define TD_B 64
#define TD_V 128
#define KC   8

__global__ __launch_bounds__(256) void out_gemm(
    const float* __restrict__ P, const float* __restrict__ yT,
    const float* __restrict__ mArr, float* __restrict__ out)
{
    __shared__ float Ys[KC][TD_B + 8];    // 8 x 72 (16B-aligned rows)
    __shared__ float Es[KC][TD_V + 4];    // 8 x 132

    int tid = threadIdx.x;
    int b0 = blockIdx.x * TD_B;   // fast dim = b-tiles (share P tile in L2)
    int v0 = blockIdx.y * TD_V;
    int vg = tid & 31;            // 32 v-groups of 4
    int bg = tid >> 5;            // 8 b-groups of 8

    float acc[8][4] = {{0.f}};

    for (int k0 = 0; k0 < K_N; k0 += KC) {
        if (tid < 128) {
            int kr = tid >> 4;  // 0..7
            int bq = tid & 15;  // float4 in b
            float4 yv = *(const float4*)(yT + (size_t)(k0 + kr) * B_N
                                            + b0 + bq * 4);
            *(float4*)&Ys[kr][bq * 4] = yv;
        }
        {
            int kr = tid >> 5;  // 0..7
            int vq = tid & 31;  // float4 in v
            int gv = v0 + vq * 4;
            int k  = k0 + kr;
            float mk = mArr[k];
            float4 e = make_float4(0.f, 0.f, 0.f, 0.f);
            if (gv + 3 < V_N) {
                float4 p = *(const float4*)(P + (size_t)k * V_N + gv);
                e = make_float4(__expf(p.x - mk), __expf(p.y - mk),
                                __expf(p.z - mk), __expf(p.w - mk));
            }
            *(float4*)&Es[kr][vq * 4] = e;
        }
        __syncthreads();

        #pragma unroll
        for (int kr = 0; kr < KC; ++kr) {
            float4 e4 = *(const float4*)&Es[kr][vg * 4];
            float ev[4] = {e4.x, e4.y, e4.z, e4.w};
            float4 ya = *(const float4*)&Ys[kr][bg * 8];
            float4 yb = *(const float4*)&Ys[kr][bg * 8 + 4];
            float yv[8] = {ya.x, ya.y, ya.z, ya.w, yb.x, yb.y, yb.z, yb.w};
            #pragma unroll
            for (int i = 0; i < 8; ++i) {
                #pragma unroll
                for (int j = 0; j < 4; ++j) {
                    acc[i][j] = fmaf(yv[i], ev[j], acc[i][j]);
                }
            }
        }
        __syncthreads();
    }

    #pragma unroll
    for (int i = 0; i < 8; ++i) {
        int b = b0 + bg * 8 + i;
        int v = v0 + vg * 4;
        float* dst = out + (size_t)b * (K_N + V_N) + K_N + v;
        if (v + 3 < V_N) {
            *(float4*)dst = make_float4(acc[i][0], acc[i][1],
                                        acc[i][2], acc[i][3]);
        } else {
            for (int j = 0; j < 4; ++j)
                if (v + j < V_N) dst[j] = acc[i][j];
        }
    }
}

// ---------------- launch ----------------
extern "C" void kernel_launch(void* const* d_in, const int* in_sizes, int n_in,
                              void* d_out, int out_size, void* d_ws, size_t ws_size,
                              hipStream_t stream) {
    const float* x    = (const float*)d_in[0];  // (B, K)
    const float* wv   = (const float*)d_in[1];  // (V, D)
    const float* mu   = (const float*)d_in[2];  // (K, D)
    const float* cw   = (const float*)d_in[3];  // (K, D)
    const float* cd   = (const float*)d_in[4];  // (K, D)
    float* out = (float*)d_out;
    float* ws  = (float*)d_ws;

    float* P     = ws + P_OFF;
    float* coef  = ws + COEF_OFF;
    float* alpha = ws + ALPHA_OFF;
    float* sArr  = ws + S_OFF;
    float* hic   = ws + HIC_OFF;
    float* mArr  = ws + M_OFF;
    float* zArr  = ws + Z_OFF;
    float* yT    = ws + YT_OFF;

    topic_prep<<<K_N, 256, 0, stream>>>(mu, cw, cd, coef, alpha, sArr, hic);

    dim3 gB((K_N + TB_K - 1) / TB_K, (V_N + TB_V - 1) / TB_V);  // (7, 782)
    logp_kernel<<<gB, 256, 0, stream>>>(wv, coef, alpha, sArr, hic, P);

    softmax_stats<<<K_N, 1024, 0, stream>>>(P, mArr, zArr);

    prep_y<<<(B_N * K_N + 255) / 256, 256, 0, stream>>>(x, zArr, yT, out);

    dim3 gD(B_N / TD_B, (V_N + TD_V - 1) / TD_V);  // (4, 782)
    out_gemm<<<gD, 256, 0, stream>>>(P, yT, mArr, out);
}

// Round 2
// 666.277 us; speedup vs baseline: 1.2866x; 1.2866x over previous
//
#include <hip/hip_runtime.h>
#include <math.h>

#define V_N 100000
#define D_N 300
#define K_N 200
#define B_N 256

#define SC 128.0f
#define SC_INV 0.0078125f

typedef _Float16 h4 __attribute__((ext_vector_type(4)));
typedef _Float16 h8 __attribute__((ext_vector_type(8)));
typedef float f4v __attribute__((ext_vector_type(4)));

// ---------------- workspace layout (floats) ----------------
// P   : K_N * V_N                      (logp, row-major K x V, fp32)
// cB  : 215040 fp16 = 107520 floats    (LDS-staged B: [kb2][c10][arr3][n112][k32])
//       arr0 = hi(-0.5*Dinv*SC_INV), arr1 = lo(same), arr2 = hi(mu*Dinv*SC_INV)
// cG  : 215040 fp16 = 107520 floats    (direct-global B: [arr3][n224][kin320])
//       arr0 = lo(mu*Dinv*SC_INV), arr1 = hi(u*SC_INV), arr2 = lo(u*SC_INV)
// alpha,s,hic,m,z : 256 each
// yT  : K_N * B_N
static constexpr size_t P_OFF     = 0;
static constexpr size_t CB_OFF    = (size_t)K_N * V_N;          // 20,000,000
static constexpr size_t CG_OFF    = CB_OFF + 107520;
static constexpr size_t ALPHA_OFF = CG_OFF + 107520;
static constexpr size_t S_OFF     = ALPHA_OFF + 256;
static constexpr size_t HIC_OFF   = S_OFF + 256;
static constexpr size_t M_OFF     = HIC_OFF + 256;
static constexpr size_t Z_OFF     = M_OFF + 256;
static constexpr size_t YT_OFF    = Z_OFF + 256;

__device__ __forceinline__ h8 ld8(const _Float16* p) {
    h8 r;
    *(h4*)&r = *(const h4*)p;
    *((h4*)&r + 1) = *(const h4*)(p + 4);
    return r;
}

// ---------------- kernel A: per-topic scalars ----------------
__global__ __launch_bounds__(256) void topic_prep(
    const float* __restrict__ mu, const float* __restrict__ w,
    const float* __restrict__ diag,
    float* __restrict__ alpha, float* __restrict__ sArr,
    float* __restrict__ hic)
{
    int k = blockIdx.x;
    int tid = threadIdx.x;
    if (k >= K_N) {
        if (tid == 0) { alpha[k] = 0.f; sArr[k] = 0.f; hic[k] = 0.f; }
        return;
    }
    float capp = 0.f, logd = 0.f, cpart = 0.f, spart = 0.f;
    for (int d = tid; d < D_N; d += 256) {
        float Dg = diag[k * D_N + d];
        float Di = 1.0f / Dg;
        float wvv = w[k * D_N + d];
        float m  = mu[k * D_N + d];
        float u  = wvv * Di;
        capp  += wvv * u;
        logd  += logf(Dg);
        cpart += m * m * Di;
        spart += m * u;
    }
    __shared__ float4 red[256];
    red[tid] = make_float4(capp, logd, cpart, spart);
    __syncthreads();
    for (int s = 128; s > 0; s >>= 1) {
        if (tid < s) {
            float4 a = red[tid], b = red[tid + s];
            red[tid] = make_float4(a.x + b.x, a.y + b.y, a.z + b.z, a.w + b.w);
        }
        __syncthreads();
    }
    if (tid == 0) {
        float4 r = red[0];
        float cap = 1.0f + r.x;
        float logdet = r.y + logf(cap);
        const float LOG2PI = 1.8378770664093453f;
        alpha[k] = -0.5f * ((float)D_N * LOG2PI + logdet + r.z);
        sArr[k]  = r.w;
        hic[k]   = 0.5f / cap;
    }
}

// ---------------- kernel A2: split coefficients to fp16 hi/lo ----------------
__global__ __launch_bounds__(256) void coef_prep(
    const float* __restrict__ mu, const float* __restrict__ w,
    const float* __restrict__ cd, _Float16* __restrict__ cB,
    _Float16* __restrict__ cG)
{
    int id = blockIdx.x * 256 + threadIdx.x;
    if (id < 215040) {
        // cB linear: (((kb*10 + c)*3 + arr)*112 + n)*32 + k
        int k  = id & 31;
        int rr = id >> 5;
        int n  = rr % 112;
        int r2 = rr / 112;
        int arr = r2 % 3;
        int r3  = r2 / 3;
        int c  = r3 % 10;
        int kb = r3 / 10;
        int ng = kb * 112 + n;
        int d  = c * 32 + k;
        float val = 0.f;
        int half = 0;
        if (ng < K_N && d < D_N) {
            float Di = 1.0f / cd[ng * D_N + d];
            if (arr == 0)      { val = -0.5f * Di * SC_INV; half = 0; }
            else if (arr == 1) { val = -0.5f * Di * SC_INV; half = 1; }
            else               { val = mu[ng * D_N + d] * Di * SC_INV; half = 0; }
        }
        _Float16 hi = (_Float16)val;
        cB[id] = half ? (_Float16)(val - (float)hi) : hi;
    } else {
        int id2 = id - 215040;
        if (id2 < 215040) {
            // cG linear: (arr*224 + ng)*320 + kin
            int kin = id2 % 320;
            int r   = id2 / 320;
            int ng  = r % 224;
            int arr = r / 224;
            float val = 0.f;
            int half = 0;
            if (ng < K_N && kin < D_N) {
                float Di = 1.0f / cd[ng * D_N + kin];
                if (arr == 0)      { val = mu[ng * D_N + kin] * Di * SC_INV; half = 1; }
                else if (arr == 1) { val = w[ng * D_N + kin] * Di * SC_INV;  half = 0; }
                else               { val = w[ng * D_N + kin] * Di * SC_INV;  half = 1; }
            }
            _Float16 hi = (_Float16)val;
            cG[id2] = half ? (_Float16)(val - (float)hi) : hi;
        }
    }
}

// ---------------- kernel B: logp via split-fp16 MFMA ----------------
// Block tile: M=128 (V) x N=112 (topics). 4 waves stacked in M (wave tile 32x112).
// grid.x = kb (2 k-blocks: topics [0,112) and [112,224), stores masked <200).
__global__ __launch_bounds__(256, 2) void logp_mfma(
    const float* __restrict__ wv, const _Float16* __restrict__ cB,
    const _Float16* __restrict__ cG, const float* __restrict__ alphaA,
    const float* __restrict__ sA, const float* __restrict__ hA,
    float* __restrict__ P)
{
    // 61056 B: As 4 arrays [128][36] fp16 (36864 B) + Bs 3 arrays [112][36] fp16 (24192 B)
    __shared__ _Float16 smem[30528];
    _Float16* As = smem;            // arr stride 4608 elems
    _Float16* Bs = smem + 18432;    // arr stride 4032 elems

    const int tid = threadIdx.x;
    const int kb = blockIdx.x;
    const int v0 = blockIdx.y * 128;
    const int lane = tid & 63;
    const int quad = lane >> 4, lr = lane & 15;
    const int wm = (tid >> 6) * 32;       // wave m offset
    const int dq = tid & 7, vr = tid >> 3;

    f4v C1[2][7], C2[2][7];
    #pragma unroll
    for (int i = 0; i < 2; ++i)
        #pragma unroll
        for (int j = 0; j < 7; ++j) {
            C1[i][j] = (f4v){0.f, 0.f, 0.f, 0.f};
            C2[i][j] = (f4v){0.f, 0.f, 0.f, 0.f};
        }

    for (int c = 0; c < 10; ++c) {
        const int d0 = c * 32;
        __syncthreads();
        // ---- stage A: 128 rows x 32 d, fp32 -> 4 split-fp16 arrays ----
        #pragma unroll
        for (int rep = 0; rep < 4; ++rep) {
            int v = vr + rep * 32;
            int gv = v0 + v;
            int d = d0 + dq * 4;
            float4 a = make_float4(0.f, 0.f, 0.f, 0.f);
            if (gv < V_N && d < D_N)
                a = *(const float4*)(wv + (size_t)gv * D_N + d);
            float av[4] = {a.x, a.y, a.z, a.w};
            h4 ah, al, qh, ql;
            #pragma unroll
            for (int j = 0; j < 4; ++j) {
                float x = av[j];
                _Float16 xh = (_Float16)x;
                ah[j] = xh;
                al[j] = (_Float16)(x - (float)xh);
                float xs = x * x;
                _Float16 sh = (_Float16)xs;
                qh[j] = sh;
                ql[j] = (_Float16)(xs - (float)sh);
            }
            int base = v * 36 + dq * 4;
            *(h4*)(As + 0 * 4608 + base) = qh;
            *(h4*)(As + 1 * 4608 + base) = ql;
            *(h4*)(As + 2 * 4608 + base) = ah;
            *(h4*)(As + 3 * 4608 + base) = al;
        }
        // ---- stage B (LDS part): contiguous 21504 B slice ----
        {
            const float4* src = (const float4*)cB + (size_t)(kb * 10 + c) * 1344;
            #pragma unroll
            for (int i = 0; i < 6; ++i) {
                int id = tid + i * 256;
                if (id < 1344) {
                    float4 val = src[id];
                    int ks = id & 3;
                    int rr = id >> 2;
                    int n = rr % 112;
                    int arr = rr / 112;
                    _Float16* dst = Bs + arr * 4032 + n * 36 + ks * 8;
                    union { float4 f; h4 h[2]; } u;
                    u.f = val;
                    *(h4*)dst = u.h[0];
                    *(h4*)(dst + 4) = u.h[1];
                }
            }
        }
        __syncthreads();

        // ---- A fragments (registers, reused across all 7 n-tiles) ----
        h8 fqh[2], fql[2], fah[2], fal[2];
        #pragma unroll
        for (int mt = 0; mt < 2; ++mt) {
            int off = (wm + mt * 16 + lr) * 36 + quad * 8;
            fqh[mt] = ld8(As + 0 * 4608 + off);
            fql[mt] = ld8(As + 1 * 4608 + off);
            fah[mt] = ld8(As + 2 * 4608 + off);
            fal[mt] = ld8(As + 3 * 4608 + off);
        }

        #pragma unroll
        for (int nt = 0; nt < 7; ++nt) {
            int boff = (nt * 16 + lr) * 36 + quad * 8;
            h8 bqh = ld8(Bs + 0 * 4032 + boff);
            h8 bql = ld8(Bs + 1 * 4032 + boff);
            h8 bmh = ld8(Bs + 2 * 4032 + boff);
            int ng = kb * 112 + nt * 16 + lr;
            const _Float16* gb = cG + (size_t)ng * 320 + c * 32 + quad * 8;
            h8 bml = *(const h8*)(gb);
            h8 buh = *(const h8*)(gb + 71680);
            h8 bul = *(const h8*)(gb + 143360);

            C1[0][nt] = __builtin_amdgcn_mfma_f32_16x16x32_f16(fqh[0], bqh, C1[0][nt], 0, 0, 0);
            C1[1][nt] = __builtin_amdgcn_mfma_f32_16x16x32_f16(fqh[1], bqh, C1[1][nt], 0, 0, 0);
            C1[0][nt] = __builtin_amdgcn_mfma_f32_16x16x32_f16(fql[0], bqh, C1[0][nt], 0, 0, 0);
            C1[1][nt] = __builtin_amdgcn_mfma_f32_16x16x32_f16(fql[1], bqh, C1[1][nt], 0, 0, 0);
            C1[0][nt] = __builtin_amdgcn_mfma_f32_16x16x32_f16(fqh[0], bql, C1[0][nt], 0, 0, 0);
            C1[1][nt] = __builtin_amdgcn_mfma_f32_16x16x32_f16(fqh[1], bql, C1[1][nt], 0, 0, 0);
            C1[0][nt] = __builtin_amdgcn_mfma_f32_16x16x32_f16(fah[0], bmh, C1[0][nt], 0, 0, 0);
            C1[1][nt] = __builtin_amdgcn_mfma_f32_16x16x32_f16(fah[1], bmh, C1[1][nt], 0, 0, 0);
            C1[0][nt] = __builtin_amdgcn_mfma_f32_16x16x32_f16(fal[0], bmh, C1[0][nt], 0, 0, 0);
            C1[1][nt] = __builtin_amdgcn_mfma_f32_16x16x32_f16(fal[1], bmh, C1[1][nt], 0, 0, 0);
            C1[0][nt] = __builtin_amdgcn_mfma_f32_16x16x32_f16(fah[0], bml, C1[0][nt], 0, 0, 0);
            C1[1][nt] = __builtin_amdgcn_mfma_f32_16x16x32_f16(fah[1], bml, C1[1][nt], 0, 0, 0);
            C2[0][nt] = __builtin_amdgcn_mfma_f32_16x16x32_f16(fah[0], buh, C2[0][nt], 0, 0, 0);
            C2[1][nt] = __builtin_amdgcn_mfma_f32_16x16x32_f16(fah[1], buh, C2[1][nt], 0, 0, 0);
            C2[0][nt] = __builtin_amdgcn_mfma_f32_16x16x32_f16(fal[0], buh, C2[0][nt], 0, 0, 0);
            C2[1][nt] = __builtin_amdgcn_mfma_f32_16x16x32_f16(fal[1], buh, C2[1][nt], 0, 0, 0);
            C2[0][nt] = __builtin_amdgcn_mfma_f32_16x16x32_f16(fah[0], bul, C2[0][nt], 0, 0, 0);
            C2[1][nt] = __builtin_amdgcn_mfma_f32_16x16x32_f16(fal[1]*(_Float16)0 + fah[1], bul, C2[1][nt], 0, 0, 0);
        }
    }

    // ---- epilogue: combine, transpose via LDS, coalesced store ----
    __syncthreads();
    float* Ct = (float*)smem;  // [112][132] fp32
    #pragma unroll
    for (int nt = 0; nt < 7; ++nt) {
        int nl = nt * 16 + lr;
        int ng = kb * 112 + nl;
        float al = alphaA[ng], sk = sA[ng], hk = hA[ng];
        #pragma unroll
        for (int mt = 0; mt < 2; ++mt) {
            f4v c1 = C1[mt][nt], c2 = C2[mt][nt];
            f4v res;
            #pragma unroll
            for (int r = 0; r < 4; ++r) {
                float t = SC * c2[r] - sk;
                res[r] = al + SC * c1[r] + hk * t * t;
            }
            *(f4v*)(Ct + nl * 132 + wm + mt * 16 + quad * 4) = res;
        }
    }
    __syncthreads();
    #pragma unroll
    for (int i = 0; i < 14; ++i) {
        int id = tid + i * 256;        // 0..3583
        int m4 = (id & 31) * 4;
        int nl = id >> 5;              // 0..111
        int kg = kb * 112 + nl;
        if (kg < K_N) {
            f4v val = *(const f4v*)(Ct + nl * 132 + m4);
            int v = v0 + m4;
            if (v + 3 < V_N) {
                *(float4*)(P + (size_t)kg * V_N + v) =
                    make_float4(val[0], val[1], val[2], val[3]);
            } else {
                for (int j = 0; j < 4; ++j)
                    if (v + j < V_N) P[(size_t)kg * V_N + v + j] = val[j];
            }
        }
    }
}

// ---------------- kernel C: per-topic online softmax stats ----------------
__global__ __launch_bounds__(1024) void softmax_stats(
    const float* __restrict__ P, float* __restrict__ mArr,
    float* __restrict__ zArr)
{
    int k = blockIdx.x;
    int tid = threadIdx.x;
    const float4* row = (const float4*)(P + (size_t)k * V_N);
    const int n4 = V_N / 4;
    float m = -INFINITY, s = 0.f;
    for (int i = tid; i < n4; i += 1024) {
        float4 x = row[i];
        float mx = fmaxf(fmaxf(x.x, x.y), fmaxf(x.z, x.w));
        if (mx > m) { s *= __expf(m - mx); m = mx; }
        s += __expf(x.x - m) + __expf(x.y - m)
           + __expf(x.z - m) + __expf(x.w - m);
    }
    __shared__ float ms[1024], ss[1024];
    ms[tid] = m; ss[tid] = s;
    __syncthreads();
    for (int off = 512; off > 0; off >>= 1) {
        if (tid < off) {
            float mo = ms[tid], so = ss[tid];
            float m2 = ms[tid + off], s2 = ss[tid + off];
            float mn = fmaxf(mo, m2);
            ms[tid] = mn;
            ss[tid] = so * __expf(mo - mn) + s2 * __expf(m2 - mn);
        }
        __syncthreads();
    }
    if (tid == 0) { mArr[k] = ms[0]; zArr[k] = ss[0]; }
}

// ---------------- kernel C2: yT = x/Z, copy x into out ----------------
__global__ __launch_bounds__(256) void prep_y(
    const float* __restrict__ x, const float* __restrict__ zArr,
    float* __restrict__ yT, float* __restrict__ out)
{
    int idx = blockIdx.x * 256 + threadIdx.x;
    if (idx < B_N * K_N) {
        int b = idx / K_N, k = idx % K_N;
        float xv = x[idx];
        out[(size_t)b * (K_N + V_N) + k] = xv;
        yT[(size_t)k * B_N + b] = xv / zArr[k];
    }
}

// ---------------- kernel D: out[b, K+v] = sum_k y[b,k]*exp(P[k,v]-m[k]) ----
#define TD_B 64
#define TD_V 128
#define KC   8

__global__ __launch_bounds__(256) void out_gemm(
    const float* __restrict__ P, const float* __restrict__ yT,
    const float* __restrict__ mArr, float* __restrict__ out)
{
    __shared__ float Ys[KC][TD_B + 8];
    __shared__ float Es[KC][TD_V + 4];

    int tid = threadIdx.x;
    int b0 = blockIdx.x * TD_B;
    int v0 = blockIdx.y * TD_V;
    int vg = tid & 31;
    int bg = tid >> 5;

    float acc[8][4] = {{0.f}};

    for (int k0 = 0; k0 < K_N; k0 += KC) {
        if (tid < 128) {
            int kr = tid >> 4;
            int bq = tid & 15;
            float4 yv = *(const float4*)(yT + (size_t)(k0 + kr) * B_N
                                            + b0 + bq * 4);
            *(float4*)&Ys[kr][bq * 4] = yv;
        }
        {
            int kr = tid >> 5;
            int vq = tid & 31;
            int gv = v0 + vq * 4;
            int k  = k0 + kr;
            float mk = mArr[k];
            float4 e = make_float4(0.f, 0.f, 0.f, 0.f);
            if (gv + 3 < V_N) {
                float4 p = *(const float4*)(P + (size_t)k * V_N + gv);
                e = make_float4(__expf(p.x - mk), __expf(p.y - mk),
                                __expf(p.z - mk), __expf(p.w - mk));
            }
            *(float4*)&Es[kr][vq * 4] = e;
        }
        __syncthreads();

        #pragma unroll
        for (int kr = 0; kr < KC; ++kr) {
            float4 e4 = *(const float4*)&Es[kr][vg * 4];
            float ev[4] = {e4.x, e4.y, e4.z, e4.w};
            float4 ya = *(const float4*)&Ys[kr][bg * 8];
            float4 yb = *(const float4*)&Ys[kr][bg * 8 + 4];
            float yv[8] = {ya.x, ya.y, ya.z, ya.w, yb.x, yb.y, yb.z, yb.w};
            #pragma unroll
            for (int i = 0; i < 8; ++i) {
                #pragma unroll
                for (int j = 0; j < 4; ++j) {
                    acc[i][j] = fmaf(yv[i], ev[j], acc[i][j]);
                }
            }
        }
        __syncthreads();
    }

    #pragma unroll
    for (int i = 0; i < 8; ++i) {
        int b = b0 + bg * 8 + i;
        int v = v0 + vg * 4;
        float* dst = out + (size_t)b * (K_N + V_N) + K_N + v;
        if (v + 3 < V_N) {
            *(float4*)dst = make_float4(acc[i][0], acc[i][1],
                                        acc[i][2], acc[i][3]);
        } else {
            for (int j = 0; j < 4; ++j)
                if (v + j < V_N) dst[j] = acc[i][j];
        }
    }
}

// ---------------- launch ----------------
extern "C" void kernel_launch(void* const* d_in, const int* in_sizes, int n_in,
                              void* d_out, int out_size, void* d_ws, size_t ws_size,
                              hipStream_t stream) {
    const float* x    = (const float*)d_in[0];  // (B, K)
    const float* wv   = (const float*)d_in[1];  // (V, D)
    const float* mu   = (const float*)d_in[2];  // (K, D)
    const float* cw   = (const float*)d_in[3];  // (K, D)
    const float* cd   = (const float*)d_in[4];  // (K, D)
    float* out = (float*)d_out;
    float* ws  = (float*)d_ws;

    float* P      = ws + P_OFF;
    _Float16* cB  = (_Float16*)(ws + CB_OFF);
    _Float16* cG  = (_Float16*)(ws + CG_OFF);
    float* alpha  = ws + ALPHA_OFF;
    float* sArr   = ws + S_OFF;
    float* hic    = ws + HIC_OFF;
    float* mArr   = ws + M_OFF;
    float* zArr   = ws + Z_OFF;
    float* yT     = ws + YT_OFF;

    topic_prep<<<256, 256, 0, stream>>>(mu, cw, cd, alpha, sArr, hic);
    coef_prep<<<1680, 256, 0, stream>>>(mu, cw, cd, cB, cG);

    dim3 gB(2, (V_N + 127) / 128);  // (2, 782)
    logp_mfma<<<gB, 256, 0, stream>>>(wv, cB, cG, alpha, sArr, hic, P);

    softmax_stats<<<K_N, 1024, 0, stream>>>(P, mArr, zArr);
    prep_y<<<(B_N * K_N + 255) / 256, 256, 0, stream>>>(x, zArr, yT, out);

    dim3 gD(B_N / TD_B, (V_N + TD_V - 1) / TD_V);  // (4, 782)
    out_gemm<<<gD, 256, 0, stream>>>(P, yT, mArr, out);
}

// Round 3
// 459.175 us; speedup vs baseline: 1.8670x; 1.4510x over previous
//
#include <hip/hip_runtime.h>
#include <math.h>

#define V_N 100000
#define D_N 300
#define K_N 200
#define B_N 256

#define SC 128.0f
#define SC_INV 0.0078125f

typedef _Float16 h4 __attribute__((ext_vector_type(4)));
typedef _Float16 h8 __attribute__((ext_vector_type(8)));
typedef float f4v __attribute__((ext_vector_type(4)));

typedef __attribute__((address_space(1))) const void gvoid;
typedef __attribute__((address_space(3))) void lvoid;

// ---------------- workspace layout (floats) ----------------
// P  : 20,000,000 (logp, K x V fp32)
// CB : 225,280 floats = 450,560 halves  (LDS image: [kb2][c10]{6 arrays [n112][32] swizzled + pad to 22528 halves})
// scalars: alpha,s,hic,m,z (256 each)
// pm/ps: 800 each (partial softmax stats)
// yF : reuses CB region (halves) after logp is done
static constexpr size_t P_OFF     = 0;
static constexpr size_t CB_OFF    = (size_t)K_N * V_N;            // 20,000,000
static constexpr size_t ALPHA_OFF = CB_OFF + 225280;
static constexpr size_t S_OFF     = ALPHA_OFF + 256;
static constexpr size_t HIC_OFF   = S_OFF + 256;
static constexpr size_t M_OFF     = HIC_OFF + 256;
static constexpr size_t Z_OFF     = M_OFF + 256;
static constexpr size_t PM_OFF    = Z_OFF + 256;
static constexpr size_t PS_OFF    = PM_OFF + 800;
static constexpr size_t YF_OFF    = CB_OFF;   // overlap (halves)

// ---------------- kernel A: per-topic scalars ----------------
__global__ __launch_bounds__(256) void topic_prep(
    const float* __restrict__ mu, const float* __restrict__ w,
    const float* __restrict__ diag,
    float* __restrict__ alpha, float* __restrict__ sArr,
    float* __restrict__ hic)
{
    int k = blockIdx.x;
    int tid = threadIdx.x;
    if (k >= K_N) {
        if (tid == 0) { alpha[k] = 0.f; sArr[k] = 0.f; hic[k] = 0.f; }
        return;
    }
    float capp = 0.f, logd = 0.f, cpart = 0.f, spart = 0.f;
    for (int d = tid; d < D_N; d += 256) {
        float Dg = diag[k * D_N + d];
        float Di = 1.0f / Dg;
        float wvv = w[k * D_N + d];
        float m  = mu[k * D_N + d];
        float u  = wvv * Di;
        capp  += wvv * u;
        logd  += logf(Dg);
        cpart += m * m * Di;
        spart += m * u;
    }
    __shared__ float4 red[256];
    red[tid] = make_float4(capp, logd, cpart, spart);
    __syncthreads();
    for (int s = 128; s > 0; s >>= 1) {
        if (tid < s) {
            float4 a = red[tid], b = red[tid + s];
            red[tid] = make_float4(a.x + b.x, a.y + b.y, a.z + b.z, a.w + b.w);
        }
        __syncthreads();
    }
    if (tid == 0) {
        float4 r = red[0];
        float cap = 1.0f + r.x;
        float logdet = r.y + logf(cap);
        const float LOG2PI = 1.8378770664093453f;
        alpha[k] = -0.5f * ((float)D_N * LOG2PI + logdet + r.z);
        sArr[k]  = r.w;
        hic[k]   = 0.5f / cap;
    }
}

// ---------------- kernel A2: build the B LDS image ----------------
// cB halves: chunk slab (kb,c) = 22528 halves; first 21504 = 6 arrays x [n112][32],
// within row n the four 16B (8-half) blocks are swizzled: pos p holds source
// quad q = (p - (n>>1)) & 3. Tail 1024 halves = zero pad (DMA overrun).
// arr: 0/1 = hi/lo(-0.5*Dinv*SC_INV), 2/3 = hi/lo(mu*Dinv*SC_INV), 4/5 = hi/lo(u*SC_INV)
__global__ __launch_bounds__(256) void coef_prep(
    const float* __restrict__ mu, const float* __restrict__ w,
    const float* __restrict__ cd, _Float16* __restrict__ cB)
{
    int id = blockIdx.x * 256 + threadIdx.x;
    if (id >= 450560) return;
    int chunk = id / 22528;
    int rem   = id % 22528;
    int kb = chunk / 10, c = chunk % 10;
    _Float16 outv = (_Float16)0.f;
    if (rem < 21504) {
        int arr = rem / 3584;
        int r2  = rem % 3584;
        int n = r2 >> 5;
        int h = r2 & 31;
        int p = h >> 3, r = h & 7;
        int q = (p - (n >> 1)) & 3;
        int d = c * 32 + q * 8 + r;
        int topic = kb * 112 + n;
        if (topic < K_N && d < D_N) {
            float Di = 1.0f / cd[topic * D_N + d];
            float val;
            if (arr < 2)      val = -0.5f * Di * SC_INV;
            else if (arr < 4) val = mu[topic * D_N + d] * Di * SC_INV;
            else              val = w[topic * D_N + d] * Di * SC_INV;
            _Float16 hi = (_Float16)val;
            outv = (arr & 1) ? (_Float16)(val - (float)hi) : hi;
        }
    }
    cB[id] = outv;
}

// ---------------- kernel B: logp via split-fp16 MFMA ----------------
// Block tile M=128 (V) x N=112 (topics), 4 waves stacked in M (wave 32x112).
// grid (2 kb, 782 vblk). LDS: As 4 arrays [128][32]h swizzled (32768 B)
//                              Bs 6 arrays [112][32]h swizzled + pad (45056 B)
__global__ __launch_bounds__(256, 2) void logp_mfma(
    const float* __restrict__ wv, const _Float16* __restrict__ cB,
    const float* __restrict__ alphaA, const float* __restrict__ sA,
    const float* __restrict__ hA, float* __restrict__ P)
{
    __shared__ _Float16 smem[38912];   // 77824 B
    _Float16* As = smem;               // arr stride 4096 halves
    _Float16* Bs = smem + 16384;       // arr stride 3584 halves

    const int tid = threadIdx.x;
    const int kb = blockIdx.x;
    const int v0 = blockIdx.y * 128;
    const int lane = tid & 63;
    const int quad = lane >> 4, lr = lane & 15;
    const int wm = (tid >> 6) * 32;
    const int dq = tid & 7, vr = tid >> 3;

    f4v C1[2][7], C2[2][7];
    #pragma unroll
    for (int i = 0; i < 2; ++i)
        #pragma unroll
        for (int j = 0; j < 7; ++j) {
            C1[i][j] = (f4v){0.f, 0.f, 0.f, 0.f};
            C2[i][j] = (f4v){0.f, 0.f, 0.f, 0.f};
        }

    const int row0 = wm + lr, row1 = wm + 16 + lr;
    const int pA = (quad + (row0 >> 1)) & 3;   // same for row1 (row1=row0+16)
    const int offA0 = row0 * 32 + pA * 8;
    const int offA1 = row1 * 32 + pA * 8;

    for (int c = 0; c < 10; ++c) {
        __syncthreads();
        // ---- B: DMA the prebuilt LDS image (11 x 4KB) ----
        {
            const _Float16* slab = cB + (size_t)(kb * 10 + c) * 22528 + tid * 8;
            _Float16* dst = Bs + tid * 8;
            #pragma unroll
            for (int it = 0; it < 11; ++it) {
                __builtin_amdgcn_global_load_lds(
                    (gvoid*)(slab + it * 2048), (lvoid*)(dst + it * 2048),
                    16, 0, 0);
            }
        }
        // ---- A: stage 128 rows x 32 d, fp32 -> 4 split-fp16 arrays ----
        const int d0 = c * 32;
        #pragma unroll
        for (int rep = 0; rep < 4; ++rep) {
            int v = vr + rep * 32;
            int gv = v0 + v;
            int d = d0 + dq * 4;
            float4 a = make_float4(0.f, 0.f, 0.f, 0.f);
            if (gv < V_N && d < D_N)
                a = *(const float4*)(wv + (size_t)gv * D_N + d);
            float av[4] = {a.x, a.y, a.z, a.w};
            h4 ah, al, qh, ql;
            #pragma unroll
            for (int j = 0; j < 4; ++j) {
                float x = av[j];
                _Float16 xh = (_Float16)x;
                ah[j] = xh;
                al[j] = (_Float16)(x - (float)xh);
                float xs = x * x;
                _Float16 sh = (_Float16)xs;
                qh[j] = sh;
                ql[j] = (_Float16)(xs - (float)sh);
            }
            int p = ((dq >> 1) + (v >> 1)) & 3;
            int base = v * 32 + p * 8 + (dq & 1) * 4;
            *(h4*)(As + 0 * 4096 + base) = qh;
            *(h4*)(As + 1 * 4096 + base) = ql;
            *(h4*)(As + 2 * 4096 + base) = ah;
            *(h4*)(As + 3 * 4096 + base) = al;
        }
        __syncthreads();

        // ---- A fragments ----
        h8 fqh0 = *(const h8*)(As + 0 * 4096 + offA0);
        h8 fqh1 = *(const h8*)(As + 0 * 4096 + offA1);
        h8 fql0 = *(const h8*)(As + 1 * 4096 + offA0);
        h8 fql1 = *(const h8*)(As + 1 * 4096 + offA1);
        h8 fah0 = *(const h8*)(As + 2 * 4096 + offA0);
        h8 fah1 = *(const h8*)(As + 2 * 4096 + offA1);
        h8 fal0 = *(const h8*)(As + 3 * 4096 + offA0);
        h8 fal1 = *(const h8*)(As + 3 * 4096 + offA1);

        h8 bf[7];
        #define LDB(arr)                                                       \
            _Pragma("unroll")                                                  \
            for (int nt = 0; nt < 7; ++nt) {                                   \
                int n = nt * 16 + lr;                                          \
                bf[nt] = *(const h8*)(Bs + (arr) * 3584 + n * 32               \
                                      + (((quad + (n >> 1)) & 3) << 3));       \
            }
        #define MF(ACC, MT, FR)                                                \
            _Pragma("unroll")                                                  \
            for (int nt = 0; nt < 7; ++nt)                                     \
                ACC[MT][nt] = __builtin_amdgcn_mfma_f32_16x16x32_f16(          \
                    FR, bf[nt], ACC[MT][nt], 0, 0, 0);

        LDB(0)                    // hi(-0.5 Dinv)
        MF(C1, 0, fqh0) MF(C1, 1, fqh1) MF(C1, 0, fql0) MF(C1, 1, fql1)
        LDB(1)                    // lo(-0.5 Dinv)
        MF(C1, 0, fqh0) MF(C1, 1, fqh1)
        LDB(2)                    // hi(mu Dinv)
        MF(C1, 0, fah0) MF(C1, 1, fah1) MF(C1, 0, fal0) MF(C1, 1, fal1)
        LDB(3)                    // lo(mu Dinv)
        MF(C1, 0, fah0) MF(C1, 1, fah1)
        LDB(4)                    // hi(u)
        MF(C2, 0, fah0) MF(C2, 1, fah1) MF(C2, 0, fal0) MF(C2, 1, fal1)
        LDB(5)                    // lo(u)
        MF(C2, 0, fah0) MF(C2, 1, fah1)
        #undef LDB
        #undef MF
    }

    // ---- epilogue: combine, transpose via LDS, coalesced store ----
    __syncthreads();
    float* Ct = (float*)smem;  // [112][132] fp32 = 59136 B
    #pragma unroll
    for (int nt = 0; nt < 7; ++nt) {
        int nl = nt * 16 + lr;
        int ng = kb * 112 + nl;
        float al = alphaA[ng], sk = sA[ng], hk = hA[ng];
        #pragma unroll
        for (int mt = 0; mt < 2; ++mt) {
            f4v c1 = C1[mt][nt], c2 = C2[mt][nt];
            f4v res;
            #pragma unroll
            for (int r = 0; r < 4; ++r) {
                float t = SC * c2[r] - sk;
                res[r] = al + SC * c1[r] + hk * t * t;
            }
            *(f4v*)(Ct + nl * 132 + wm + mt * 16 + quad * 4) = res;
        }
    }
    __syncthreads();
    #pragma unroll
    for (int i = 0; i < 14; ++i) {
        int id = tid + i * 256;        // 0..3583
        int m4 = (id & 31) * 4;
        int nl = id >> 5;              // 0..111
        int kg = kb * 112 + nl;
        if (kg < K_N) {
            f4v val = *(const f4v*)(Ct + nl * 132 + m4);
            int v = v0 + m4;
            if (v + 3 < V_N) {
                *(float4*)(P + (size_t)kg * V_N + v) =
                    make_float4(val[0], val[1], val[2], val[3]);
            } else {
                for (int j = 0; j < 4; ++j)
                    if (v + j < V_N) P[(size_t)kg * V_N + v + j] = val[j];
            }
        }
    }
}

// ---------------- kernel C: partial softmax stats (4 parts per topic) ------
__global__ __launch_bounds__(256) void softmax_stats(
    const float* __restrict__ P, float* __restrict__ pm,
    float* __restrict__ ps)
{
    int k = blockIdx.x >> 2, part = blockIdx.x & 3;
    int tid = threadIdx.x;
    const float4* row = (const float4*)(P + (size_t)k * V_N) + part * 6250;
    float m = -INFINITY, s = 0.f;
    for (int i = tid; i < 6250; i += 256) {
        float4 x = row[i];
        float mx = fmaxf(fmaxf(x.x, x.y), fmaxf(x.z, x.w));
        if (mx > m) { s *= __expf(m - mx); m = mx; }
        s += __expf(x.x - m) + __expf(x.y - m)
           + __expf(x.z - m) + __expf(x.w - m);
    }
    __shared__ float ms[256], ss[256];
    ms[tid] = m; ss[tid] = s;
    __syncthreads();
    for (int off = 128; off > 0; off >>= 1) {
        if (tid < off) {
            float mo = ms[tid], so = ss[tid];
            float m2 = ms[tid + off], s2 = ss[tid + off];
            float mn = fmaxf(mo, m2);
            ms[tid] = mn;
            ss[tid] = so * __expf(mo - mn) + s2 * __expf(m2 - mn);
        }
        __syncthreads();
    }
    if (tid == 0) { pm[blockIdx.x] = ms[0]; ps[blockIdx.x] = ss[0]; }
}

__global__ __launch_bounds__(256) void stats_merge(
    const float* __restrict__ pm, const float* __restrict__ ps,
    float* __restrict__ mArr, float* __restrict__ zArr)
{
    int k = threadIdx.x;
    if (k < K_N) {
        float m = -INFINITY, s = 0.f;
        #pragma unroll
        for (int p = 0; p < 4; ++p) {
            float m2 = pm[k * 4 + p], s2 = ps[k * 4 + p];
            float mn = fmaxf(m, m2);
            s = s * __expf(m - mn) + s2 * __expf(m2 - mn);
            m = mn;
        }
        mArr[k] = m; zArr[k] = s;
    }
}

// ---------------- kernel C2: yF (MFMA B-layout fp16) + x copy --------------
// yF[kc7][quad4][b256][j8] = x[b][kc*32+quad*8+j] / Z[k]  (0 for k>=200)
__global__ __launch_bounds__(256) void prep_y(
    const float* __restrict__ x, const float* __restrict__ zArr,
    _Float16* __restrict__ yF, float* __restrict__ out)
{
    int id = blockIdx.x * 256 + threadIdx.x;
    if (id < 57344) {
        int j = id & 7;
        int b = (id >> 3) & 255;
        int q = (id >> 11) & 3;
        int kc = id >> 13;
        int k = kc * 32 + q * 8 + j;
        float v = 0.f;
        if (k < K_N) v = x[b * K_N + k] / zArr[k];
        yF[id] = (_Float16)v;
    } else {
        int id2 = id - 57344;
        if (id2 < B_N * K_N) {
            int b = id2 / K_N, k = id2 % K_N;
            out[(size_t)b * (K_N + V_N) + k] = x[id2];
        }
    }
}

// ---------------- kernel D: out = y @ softmax-weights via fp16 MFMA --------
// Block: v-tile 128 (M, 4 waves x 2 mt), b-tile 64 (N, 4 nt). grid (4 b, 782 v).
__global__ __launch_bounds__(256) void out_gemm(
    const float* __restrict__ P, const _Float16* __restrict__ yF,
    const float* __restrict__ mArr, float* __restrict__ out)
{
    __shared__ float Es[32][134];   // P chunk minus m_k; stride 134 (2-way max)

    const int tid = threadIdx.x;
    const int b0 = blockIdx.x * 64;
    const int v0 = blockIdx.y * 128;
    const int lane = tid & 63;
    const int quad = lane >> 4, lr = lane & 15;
    const int wm = (tid >> 6) * 32;

    f4v acc[2][4];
    #pragma unroll
    for (int i = 0; i < 2; ++i)
        #pragma unroll
        for (int j = 0; j < 4; ++j) acc[i][j] = (f4v){0.f, 0.f, 0.f, 0.f};

    const int kr = tid >> 3;       // 0..31 (staging row)
    const int vq = tid & 7;

    for (int kc = 0; kc < 7; ++kc) {
        __syncthreads();
        int k = kc * 32 + kr;
        bool kok = k < K_N;
        float mk = kok ? mArr[k] : 0.f;
        #pragma unroll
        for (int i = 0; i < 4; ++i) {
            int vv = (vq + i * 8) * 4;
            float4 pv;
            if (kok && v0 + vv + 3 < V_N) {
                pv = *(const float4*)(P + (size_t)k * V_N + v0 + vv);
                pv = make_float4(pv.x - mk, pv.y - mk, pv.z - mk, pv.w - mk);
            } else {
                pv = make_float4(-1e30f, -1e30f, -1e30f, -1e30f);
            }
            *(float2*)&Es[kr][vv]     = make_float2(pv.x, pv.y);
            *(float2*)&Es[kr][vv + 2] = make_float2(pv.z, pv.w);
        }
        __syncthreads();

        // y fragments (B operand): col b = b0+nt*16+lr, k = quad*8+j
        h8 yf[4];
        #pragma unroll
        for (int nt = 0; nt < 4; ++nt)
            yf[nt] = *(const h8*)(yF + (((size_t)(kc * 4 + quad) * 256)
                                        + b0 + nt * 16 + lr) * 8);

        // A fragments: row v = wm+mt*16+lr, k = quad*8+j -> exp + cvt
        #pragma unroll
        for (int mt = 0; mt < 2; ++mt) {
            int row = wm + mt * 16 + lr;
            h8 af;
            #pragma unroll
            for (int j = 0; j < 8; ++j)
                af[j] = (_Float16)__expf(Es[quad * 8 + j][row]);
            #pragma unroll
            for (int nt = 0; nt < 4; ++nt)
                acc[mt][nt] = __builtin_amdgcn_mfma_f32_16x16x32_f16(
                    af, yf[nt], acc[mt][nt], 0, 0, 0);
        }
    }

    // store: C row = v (quad*4+reg), col = b (lr)
    #pragma unroll
    for (int mt = 0; mt < 2; ++mt) {
        int v = v0 + wm + mt * 16 + quad * 4;
        #pragma unroll
        for (int nt = 0; nt < 4; ++nt) {
            int b = b0 + nt * 16 + lr;
            float* dst = out + (size_t)b * (K_N + V_N) + K_N + v;
            f4v a = acc[mt][nt];
            if (v + 3 < V_N) {
                *(float4*)dst = make_float4(a[0], a[1], a[2], a[3]);
            } else {
                for (int j = 0; j < 4; ++j)
                    if (v + j < V_N) dst[j] = a[j];
            }
        }
    }
}

// ---------------- launch ----------------
extern "C" void kernel_launch(void* const* d_in, const int* in_sizes, int n_in,
                              void* d_out, int out_size, void* d_ws, size_t ws_size,
                              hipStream_t stream) {
    const float* x    = (const float*)d_in[0];  // (B, K)
    const float* wv   = (const float*)d_in[1];  // (V, D)
    const float* mu   = (const float*)d_in[2];  // (K, D)
    const float* cw   = (const float*)d_in[3];  // (K, D)
    const float* cd   = (const float*)d_in[4];  // (K, D)
    float* out = (float*)d_out;
    float* ws  = (float*)d_ws;

    float* P      = ws + P_OFF;
    _Float16* cB  = (_Float16*)(ws + CB_OFF);
    float* alpha  = ws + ALPHA_OFF;
    float* sArr   = ws + S_OFF;
    float* hic    = ws + HIC_OFF;
    float* mArr   = ws + M_OFF;
    float* zArr   = ws + Z_OFF;
    float* pm     = ws + PM_OFF;
    float* ps     = ws + PS_OFF;
    _Float16* yF  = (_Float16*)(ws + YF_OFF);   // overlaps cB (post-logp)

    topic_prep<<<256, 256, 0, stream>>>(mu, cw, cd, alpha, sArr, hic);
    coef_prep<<<1760, 256, 0, stream>>>(mu, cw, cd, cB);

    dim3 gB(2, (V_N + 127) / 128);  // (2, 782)
    logp_mfma<<<gB, 256, 0, stream>>>(wv, cB, alpha, sArr, hic, P);

    softmax_stats<<<K_N * 4, 256, 0, stream>>>(P, pm, ps);
    stats_merge<<<1, 256, 0, stream>>>(pm, ps, mArr, zArr);
    prep_y<<<(57344 + B_N * K_N + 255) / 256, 256, 0, stream>>>(x, zArr, yF, out);

    dim3 gD(4, (V_N + 127) / 128);  // (4, 782)
    out_gemm<<<gD, 256, 0, stream>>>(P, yF, mArr, out);
}